// Round 2
// baseline (55.338 us; speedup 1.0000x reference)
//
#include <hip/hip_runtime.h>
#include <hip/hip_bf16.h>

// Problem constants (from reference): B=8192, MN=64*64=4096, D=128
#define NB   8192
#define NMN  4096
#define ND   128

typedef __attribute__((ext_vector_type(8))) short bf16x8;  // 8 bf16 = 4 VGPRs
typedef __attribute__((ext_vector_type(4))) float f32x4;
typedef __attribute__((ext_vector_type(2))) float f32x2;

// ---------------------------------------------------------------------------
// Prepass: fp32 -> bf16 conversion + exact fp32 row-norms.
// 256 threads = 4 waves; each wave handles one row (128 floats, float2/lane).
// ---------------------------------------------------------------------------
__global__ __launch_bounds__(256) void som_prep(const float* __restrict__ batch,
                                                const float* __restrict__ weights,
                                                __hip_bfloat16* __restrict__ abf,
                                                __hip_bfloat16* __restrict__ bbf,
                                                float* __restrict__ a2,
                                                float* __restrict__ b2) {
    const int wid  = threadIdx.x >> 6;
    const int lane = threadIdx.x & 63;
    const int row  = blockIdx.x * 4 + wid;   // (NB+NMN)/4 = 3072 blocks

    const float* src;
    __hip_bfloat16* dst;
    float* norm;
    if (row < NB) {
        src = batch + (size_t)row * ND;
        dst = abf + (size_t)row * ND;
        norm = a2 + row;
    } else {
        const int r = row - NB;
        src = weights + (size_t)r * ND;
        dst = bbf + (size_t)r * ND;
        norm = b2 + r;
    }

    const f32x2 v = *reinterpret_cast<const f32x2*>(src + lane * 2);

    __hip_bfloat162 h;
    h.x = __float2bfloat16(v.x);
    h.y = __float2bfloat16(v.y);
    *reinterpret_cast<__hip_bfloat162*>(dst + lane * 2) = h;

    float p = v.x * v.x + v.y * v.y;
    #pragma unroll
    for (int off = 32; off > 0; off >>= 1) p += __shfl_down(p, off, 64);
    if (lane == 0) norm[0] = p;
}

// ---------------------------------------------------------------------------
// Main GEMM: out[b][w] = a2[b] + b2[w] - 2 * dot(A[b], W[w])
// 128x128 block tile, 256 threads = 4 waves in 2x2, each wave owns
// 64(batch) x 64(weight). K = 128 -> 4 k-steps of mfma_f32_16x16x32_bf16.
//
// OPERANDS SWAPPED vs naive: weight frag is the MFMA A-operand, batch frag
// the B-operand. C/D mapping (col=lane&15, row=(lane>>4)*4+reg) then gives:
//   D col  = batch row   = lane&15
//   D row  = weight col  = (lane>>4)*4 + reg   -> 4 CONSECUTIVE output cols
// so each fragment's 4 accumulator regs store as ONE float4 (nontemporal).
// ---------------------------------------------------------------------------
__global__ __launch_bounds__(256) void som_gemm(const __hip_bfloat16* __restrict__ abf,
                                                const __hip_bfloat16* __restrict__ bbf,
                                                const float* __restrict__ a2,
                                                const float* __restrict__ b2,
                                                float* __restrict__ out) {
    const int bx   = blockIdx.x;
    const int brow = (bx >> 5) << 7;   // 64 row-blocks (batch)
    const int bcol = (bx & 31) << 7;   // 32 col-blocks (weights)

    const int tid  = threadIdx.x;
    const int lane = tid & 63;
    const int wid  = tid >> 6;
    const int wr   = wid >> 1;         // wave row (batch dim) 0..1
    const int wc   = wid & 1;          // wave col (weight dim) 0..1
    const int l15  = lane & 15;
    const int l4   = lane >> 4;

    const bf16x8* A8 = reinterpret_cast<const bf16x8*>(abf);
    const bf16x8* B8 = reinterpret_cast<const bf16x8*>(bbf);

    // element-of-8 indices; row stride = ND/8 = 16
    const int abase = (brow + wr * 64 + l15) * (ND / 8) + l4;  // batch rows
    const int bbase = (bcol + wc * 64 + l15) * (ND / 8) + l4;  // weight rows

    f32x4 acc[4][4];   // [n = weight frag][m = batch frag]
    #pragma unroll
    for (int n = 0; n < 4; ++n)
        #pragma unroll
        for (int m = 0; m < 4; ++m)
            acc[n][m] = (f32x4){0.f, 0.f, 0.f, 0.f};

    #pragma unroll
    for (int kk = 0; kk < 4; ++kk) {
        bf16x8 bat[4], wgt[4];
        #pragma unroll
        for (int m = 0; m < 4; ++m) bat[m] = A8[abase + m * 256 + kk * 4];
        #pragma unroll
        for (int n = 0; n < 4; ++n) wgt[n] = B8[bbase + n * 256 + kk * 4];
        #pragma unroll
        for (int n = 0; n < 4; ++n)
            #pragma unroll
            for (int m = 0; m < 4; ++m)
                acc[n][m] = __builtin_amdgcn_mfma_f32_16x16x32_bf16(wgt[n], bat[m], acc[n][m], 0, 0, 0);
    }

    // Epilogue:
    //   b = brow + wr*64 + m*16 + l15
    //   w = bcol + wc*64 + n*16 + l4*4 + reg   (reg = 0..3 contiguous)
    float a2v[4];
    #pragma unroll
    for (int m = 0; m < 4; ++m) a2v[m] = a2[brow + wr * 64 + m * 16 + l15];

    f32x4 b2v[4];
    #pragma unroll
    for (int n = 0; n < 4; ++n)
        b2v[n] = *reinterpret_cast<const f32x4*>(&b2[bcol + wc * 64 + n * 16 + l4 * 4]);

    const int wcolbase = bcol + wc * 64 + l4 * 4;
    #pragma unroll
    for (int m = 0; m < 4; ++m) {
        const size_t rowoff = (size_t)(brow + wr * 64 + m * 16 + l15) * NMN;
        #pragma unroll
        for (int n = 0; n < 4; ++n) {
            f32x4 val = a2v[m] + b2v[n] - 2.0f * acc[n][m];
            __builtin_nontemporal_store(val,
                reinterpret_cast<f32x4*>(out + rowoff + wcolbase + n * 16));
        }
    }
}

// ---------------------------------------------------------------------------
extern "C" void kernel_launch(void* const* d_in, const int* in_sizes, int n_in,
                              void* d_out, int out_size, void* d_ws, size_t ws_size,
                              hipStream_t stream) {
    const float* batch   = (const float*)d_in[0];   // (8192, 128) fp32
    const float* weights = (const float*)d_in[1];   // (4096, 128) fp32
    float* out = (float*)d_out;                     // (8192, 4096) fp32

    // workspace layout (16B-aligned regions):
    //   a2  : 8192 * 4          =   32768 B @ 0
    //   b2  : 4096 * 4          =   16384 B @ 32768
    //   abf : 8192 * 128 * 2    = 2097152 B @ 49152
    //   bbf : 4096 * 128 * 2    = 1048576 B @ 2146304
    char* ws = (char*)d_ws;
    float* a2 = (float*)(ws);
    float* b2 = (float*)(ws + 32768);
    __hip_bfloat16* abf = (__hip_bfloat16*)(ws + 49152);
    __hip_bfloat16* bbf = (__hip_bfloat16*)(ws + 49152 + 2097152);

    som_prep<<<dim3((NB + NMN) / 4), dim3(256), 0, stream>>>(batch, weights, abf, bbf, a2, b2);

    // grid: 64 row-blocks * 32 col-blocks = 2048 blocks
    som_gemm<<<dim3(2048), dim3(256), 0, stream>>>(abf, bbf, a2, b2, out);
}

// Round 3
// 39.822 us; speedup vs baseline: 1.3896x; 1.3896x over previous
//
#include <hip/hip_runtime.h>
#include <hip/hip_bf16.h>

// Problem constants (from reference): B=8192, MN=64*64=4096, D=128
#define NB   8192
#define NMN  4096
#define ND   128

typedef __attribute__((ext_vector_type(8))) short bf16x8;  // 8 bf16 = 16 B
typedef __attribute__((ext_vector_type(8))) short short8;
typedef __attribute__((ext_vector_type(4))) float f32x4;

// ---------------------------------------------------------------------------
// Packed fragment layout for MFMA operands:
//   array viewed in 16B chunks: chunk_idx = (row>>4)*256 + q*16 + (row&15)
// where q = k-chunk (16B = 8 bf16 along K), row = matrix row.
// A wave's fragment load (fixed panel, fixed kk) reads chunks
//   base + l4*16 + l15  -> 64 consecutive 16B chunks = 1 KB contiguous.
// ---------------------------------------------------------------------------

// Prep: fp32 -> bf16 packed layout + exact fp32 row-norms.
// Block = 256 threads = 4 waves; each wave handles 4 rows (lane -> rof,q).
__global__ __launch_bounds__(256) void som_prep(const float* __restrict__ batch,
                                                const float* __restrict__ weights,
                                                __hip_bfloat16* __restrict__ apk,
                                                __hip_bfloat16* __restrict__ wpk,
                                                float* __restrict__ a2,
                                                float* __restrict__ b2) {
    const int wid  = threadIdx.x >> 6;
    const int lane = threadIdx.x & 63;
    const int rof  = lane >> 4;    // row within wave's 4-row group
    const int q    = lane & 15;    // 16B k-chunk index (8 floats)

    int row = blockIdx.x * 16 + wid * 4 + rof;   // 768 blocks * 16 rows

    const float* src;
    __hip_bfloat16* dst;
    float* norm;
    if (row < NB) {
        src = batch;  dst = apk; norm = a2;
    } else {
        row -= NB;
        src = weights; dst = wpk; norm = b2;
    }

    // coalesced read: 32B per lane, wave reads 4 rows x 512B contiguous
    const f32x4 v0 = *reinterpret_cast<const f32x4*>(src + (size_t)row * ND + q * 8);
    const f32x4 v1 = *reinterpret_cast<const f32x4*>(src + (size_t)row * ND + q * 8 + 4);

    __hip_bfloat16 tmp[8];
    tmp[0] = __float2bfloat16(v0.x); tmp[1] = __float2bfloat16(v0.y);
    tmp[2] = __float2bfloat16(v0.z); tmp[3] = __float2bfloat16(v0.w);
    tmp[4] = __float2bfloat16(v1.x); tmp[5] = __float2bfloat16(v1.y);
    tmp[6] = __float2bfloat16(v1.z); tmp[7] = __float2bfloat16(v1.w);

    const int chunk = (row >> 4) * 256 + q * 16 + (row & 15);
    *reinterpret_cast<short8*>(dst + (size_t)chunk * 8) =
        *reinterpret_cast<short8*>(tmp);

    // row norm: sum of squares over this lane's 8 elems, reduce across the
    // 16 q-lanes of the same row (xor over low 4 lane bits)
    float p = v0.x * v0.x + v0.y * v0.y + v0.z * v0.z + v0.w * v0.w
            + v1.x * v1.x + v1.y * v1.y + v1.z * v1.z + v1.w * v1.w;
    #pragma unroll
    for (int off = 1; off < 16; off <<= 1) p += __shfl_xor(p, off, 64);
    if (q == 0) norm[row] = p;
}

// ---------------------------------------------------------------------------
// GEMM: out[b][w] = a2[b] + b2[w] - 2 * dot(A[b], W[w])
// 128x128 block tile, 4 waves (2x2), each wave 64(batch) x 64(weight).
// K=128 -> 4 k-steps of mfma_f32_16x16x32_bf16. No LDS, no barriers:
// packed layout makes every fragment load 1 KB contiguous from L2.
// Operands swapped (weights = A-op) so each lane's 4 acc regs are 4
// consecutive output columns -> one float4 store.
// ---------------------------------------------------------------------------
__global__ __launch_bounds__(256) void som_gemm(const __hip_bfloat16* __restrict__ apk_,
                                                const __hip_bfloat16* __restrict__ wpk_,
                                                const float* __restrict__ a2,
                                                const float* __restrict__ b2,
                                                float* __restrict__ out) {
    // XCD-aware swizzle: 2048 blocks, 8 XCDs, 256 work-items per XCD chunk
    const int bx = blockIdx.x;
    const int w  = (bx & 7) * 256 + (bx >> 3);
    const int brow = (w >> 5) << 7;   // 64 row-blocks (batch)
    const int bcol = (w & 31) << 7;   // 32 col-blocks (weights)

    const int tid  = threadIdx.x;
    const int lane = tid & 63;
    const int wid  = tid >> 6;
    const int wr   = wid >> 1;         // wave row (batch dim) 0..1
    const int wc   = wid & 1;          // wave col (weight dim) 0..1
    const int l15  = lane & 15;
    const int l4   = lane >> 4;

    const bf16x8* A = reinterpret_cast<const bf16x8*>(apk_);
    const bf16x8* W = reinterpret_cast<const bf16x8*>(wpk_);

    // panel bases (16-row panels); fragment (m|n, kk) at:
    //   (panel + m)*256 + (kk*4 + l4)*16 + l15
    const int aoff = ((brow >> 4) + wr * 4) * 256 + l4 * 16 + l15;
    const int woff = ((bcol >> 4) + wc * 4) * 256 + l4 * 16 + l15;

    f32x4 acc[4][4];   // [m = batch frag][n = weight frag]
    #pragma unroll
    for (int m = 0; m < 4; ++m)
        #pragma unroll
        for (int n = 0; n < 4; ++n)
            acc[m][n] = (f32x4){0.f, 0.f, 0.f, 0.f};

    #pragma unroll
    for (int kk = 0; kk < 4; ++kk) {
        bf16x8 bat[4], wgt[4];
        #pragma unroll
        for (int m = 0; m < 4; ++m) bat[m] = A[aoff + m * 256 + kk * 64];
        #pragma unroll
        for (int n = 0; n < 4; ++n) wgt[n] = W[woff + n * 256 + kk * 64];
        #pragma unroll
        for (int m = 0; m < 4; ++m)
            #pragma unroll
            for (int n = 0; n < 4; ++n)
                acc[m][n] = __builtin_amdgcn_mfma_f32_16x16x32_bf16(wgt[n], bat[m], acc[m][n], 0, 0, 0);
    }

    // Epilogue: D col = batch = l15, D row = weight = l4*4 + reg (contiguous)
    float a2v[4];
    #pragma unroll
    for (int m = 0; m < 4; ++m) a2v[m] = a2[brow + wr * 64 + m * 16 + l15];

    f32x4 b2v[4];
    #pragma unroll
    for (int n = 0; n < 4; ++n)
        b2v[n] = *reinterpret_cast<const f32x4*>(&b2[bcol + wc * 64 + n * 16 + l4 * 4]);

    const int wcolbase = bcol + wc * 64 + l4 * 4;
    #pragma unroll
    for (int m = 0; m < 4; ++m) {
        const size_t rowoff = (size_t)(brow + wr * 64 + m * 16 + l15) * NMN;
        #pragma unroll
        for (int n = 0; n < 4; ++n) {
            f32x4 val = a2v[m] + b2v[n] - 2.0f * acc[m][n];
            *reinterpret_cast<f32x4*>(out + rowoff + wcolbase + n * 16) = val;
        }
    }
}

// ---------------------------------------------------------------------------
extern "C" void kernel_launch(void* const* d_in, const int* in_sizes, int n_in,
                              void* d_out, int out_size, void* d_ws, size_t ws_size,
                              hipStream_t stream) {
    const float* batch   = (const float*)d_in[0];   // (8192, 128) fp32
    const float* weights = (const float*)d_in[1];   // (4096, 128) fp32
    float* out = (float*)d_out;                     // (8192, 4096) fp32

    // workspace layout (16B-aligned regions):
    //   a2  : 8192 * 4          =   32768 B @ 0
    //   b2  : 4096 * 4          =   16384 B @ 32768
    //   apk : 8192 * 128 * 2    = 2097152 B @ 49152   (packed fragment layout)
    //   wpk : 4096 * 128 * 2    = 1048576 B @ 2146304
    char* ws = (char*)d_ws;
    float* a2 = (float*)(ws);
    float* b2 = (float*)(ws + 32768);
    __hip_bfloat16* apk = (__hip_bfloat16*)(ws + 49152);
    __hip_bfloat16* wpk = (__hip_bfloat16*)(ws + 49152 + 2097152);

    // (NB + NMN) / 16 = 768 blocks
    som_prep<<<dim3((NB + NMN) / 16), dim3(256), 0, stream>>>(batch, weights, apk, wpk, a2, b2);

    // 64 row-blocks * 32 col-blocks = 2048 blocks
    som_gemm<<<dim3(2048), dim3(256), 0, stream>>>(apk, wpk, a2, b2, out);
}

// Round 4
// 37.858 us; speedup vs baseline: 1.4617x; 1.0519x over previous
//
#include <hip/hip_runtime.h>
#include <hip/hip_bf16.h>

// Problem constants (from reference): B=8192, MN=64*64=4096, D=128
#define NB   8192
#define NMN  4096
#define ND   128

typedef __attribute__((ext_vector_type(8))) short bf16x8;  // 8 bf16 = 16 B
typedef __attribute__((ext_vector_type(8))) short short8;
typedef __attribute__((ext_vector_type(4))) float f32x4;

// ---------------------------------------------------------------------------
// Packed fragment layout for MFMA operands:
//   array viewed in 16B chunks: chunk_idx = (row>>4)*256 + q*16 + (row&15)
// where q = 16B k-chunk (8 bf16 along K), row = matrix row.
// A wave's fragment load (fixed panel, fixed kk) reads chunks
//   base + l4*16 + l15  -> 64 consecutive 16B chunks = 1 KB contiguous.
// ---------------------------------------------------------------------------

// Prep: fp32 -> bf16 packed layout + exact fp32 row-norms.
__global__ __launch_bounds__(256) void som_prep(const float* __restrict__ batch,
                                                const float* __restrict__ weights,
                                                __hip_bfloat16* __restrict__ apk,
                                                __hip_bfloat16* __restrict__ wpk,
                                                float* __restrict__ a2,
                                                float* __restrict__ b2) {
    const int wid  = threadIdx.x >> 6;
    const int lane = threadIdx.x & 63;
    const int rof  = lane >> 4;    // row within wave's 4-row group
    const int q    = lane & 15;    // 16B k-chunk index (8 floats)

    int row = blockIdx.x * 16 + wid * 4 + rof;   // 768 blocks * 16 rows

    const float* src;
    __hip_bfloat16* dst;
    float* norm;
    if (row < NB) {
        src = batch;  dst = apk; norm = a2;
    } else {
        row -= NB;
        src = weights; dst = wpk; norm = b2;
    }

    const f32x4 v0 = *reinterpret_cast<const f32x4*>(src + (size_t)row * ND + q * 8);
    const f32x4 v1 = *reinterpret_cast<const f32x4*>(src + (size_t)row * ND + q * 8 + 4);

    __hip_bfloat16 tmp[8];
    tmp[0] = __float2bfloat16(v0.x); tmp[1] = __float2bfloat16(v0.y);
    tmp[2] = __float2bfloat16(v0.z); tmp[3] = __float2bfloat16(v0.w);
    tmp[4] = __float2bfloat16(v1.x); tmp[5] = __float2bfloat16(v1.y);
    tmp[6] = __float2bfloat16(v1.z); tmp[7] = __float2bfloat16(v1.w);

    const int chunk = (row >> 4) * 256 + q * 16 + (row & 15);
    *reinterpret_cast<short8*>(dst + (size_t)chunk * 8) =
        *reinterpret_cast<short8*>(tmp);

    float p = v0.x * v0.x + v0.y * v0.y + v0.z * v0.z + v0.w * v0.w
            + v1.x * v1.x + v1.y * v1.y + v1.z * v1.z + v1.w * v1.w;
    #pragma unroll
    for (int off = 1; off < 16; off <<= 1) p += __shfl_xor(p, off, 64);
    if (q == 0) norm[row] = p;
}

// ---------------------------------------------------------------------------
// GEMM: out[b][w] = a2[b] + b2[w] - 2 * dot(A[b], W[w])
// 128x128 block tile, 4 waves (2x2), each wave 64(batch) x 64(weight).
// K=128 -> 4 k-steps of mfma_f32_16x16x32_bf16, fragments straight from
// L2-resident packed copies (1KB contiguous per load instr, no barriers).
//
// Epilogue: per-wave LDS transpose so global stores are row-contiguous.
//   MFMA D layout (operands swapped, weights = A-op):
//     batch row (within wave) = m*16 + l15
//     weight col               = n*16 + l4*4 + reg   (f32x4-contiguous)
//   Stage one m-subtile (16 rows x 64 cols f32) per wave in LDS with a
//   16B-chunk XOR swizzle (chunk ^= row&15) -> both ds_write_b128 and
//   ds_read_b128 hit the 8-words/bank optimum. Read back 4 rows x 256B
//   per instruction and nontemporal-store full cache lines.
// ---------------------------------------------------------------------------
__global__ __launch_bounds__(256) void som_gemm(const __hip_bfloat16* __restrict__ apk_,
                                                const __hip_bfloat16* __restrict__ wpk_,
                                                const float* __restrict__ a2,
                                                const float* __restrict__ b2,
                                                float* __restrict__ out) {
    // XCD-aware swizzle: 2048 blocks, 8 XCDs, 256 blocks per XCD chunk
    const int bx = blockIdx.x;
    const int w  = (bx & 7) * 256 + (bx >> 3);
    const int brow = (w >> 5) << 7;   // 64 row-blocks (batch)
    const int bcol = (w & 31) << 7;   // 32 col-blocks (weights)

    const int tid  = threadIdx.x;
    const int lane = tid & 63;
    const int wid  = tid >> 6;
    const int wr   = wid >> 1;         // wave row (batch dim) 0..1
    const int wc   = wid & 1;          // wave col (weight dim) 0..1
    const int l15  = lane & 15;
    const int l4   = lane >> 4;

    const bf16x8* A = reinterpret_cast<const bf16x8*>(apk_);
    const bf16x8* W = reinterpret_cast<const bf16x8*>(wpk_);

    const int aoff = ((brow >> 4) + wr * 4) * 256 + l4 * 16 + l15;
    const int woff = ((bcol >> 4) + wc * 4) * 256 + l4 * 16 + l15;

    f32x4 acc[4][4];   // [m = batch frag][n = weight frag]
    #pragma unroll
    for (int m = 0; m < 4; ++m)
        #pragma unroll
        for (int n = 0; n < 4; ++n)
            acc[m][n] = (f32x4){0.f, 0.f, 0.f, 0.f};

    #pragma unroll
    for (int kk = 0; kk < 4; ++kk) {
        bf16x8 bat[4], wgt[4];
        #pragma unroll
        for (int m = 0; m < 4; ++m) bat[m] = A[aoff + m * 256 + kk * 64];
        #pragma unroll
        for (int n = 0; n < 4; ++n) wgt[n] = W[woff + n * 256 + kk * 64];
        #pragma unroll
        for (int m = 0; m < 4; ++m)
            #pragma unroll
            for (int n = 0; n < 4; ++n)
                acc[m][n] = __builtin_amdgcn_mfma_f32_16x16x32_bf16(wgt[n], bat[m], acc[m][n], 0, 0, 0);
    }

    // ---- epilogue ----
    __shared__ float strip[4][16][64];   // 16 KB, one 4KB strip per wave
    f32x4* strip16 = reinterpret_cast<f32x4*>(&strip[wid][0][0]);

    float a2v[4];
    #pragma unroll
    for (int m = 0; m < 4; ++m) a2v[m] = a2[brow + wr * 64 + m * 16 + l15];

    f32x4 b2v[4];
    #pragma unroll
    for (int n = 0; n < 4; ++n)
        b2v[n] = *reinterpret_cast<const f32x4*>(&b2[bcol + wc * 64 + n * 16 + l4 * 4]);

    const size_t orow_base = (size_t)(brow + wr * 64);
    const int    ocol      = bcol + wc * 64 + l15 * 4;

    #pragma unroll
    for (int m = 0; m < 4; ++m) {
        // stage: strip[row=l15][chunk = (n*4+l4) ^ l15]  (16B chunks)
        #pragma unroll
        for (int n = 0; n < 4; ++n) {
            f32x4 val = a2v[m] + b2v[n] - 2.0f * acc[m][n];
            strip16[l15 * 16 + ((n * 4 + l4) ^ l15)] = val;
        }
        // drain: row r = 4j + l4, chunk l15 stored at l15 ^ r
        #pragma unroll
        for (int j = 0; j < 4; ++j) {
            const int r = 4 * j + l4;
            f32x4 val = strip16[r * 16 + (l15 ^ r)];
            __builtin_nontemporal_store(val,
                reinterpret_cast<f32x4*>(out + (orow_base + m * 16 + r) * NMN + ocol));
        }
    }
}

// ---------------------------------------------------------------------------
extern "C" void kernel_launch(void* const* d_in, const int* in_sizes, int n_in,
                              void* d_out, int out_size, void* d_ws, size_t ws_size,
                              hipStream_t stream) {
    const float* batch   = (const float*)d_in[0];   // (8192, 128) fp32
    const float* weights = (const float*)d_in[1];   // (4096, 128) fp32
    float* out = (float*)d_out;                     // (8192, 4096) fp32

    // workspace layout:
    //   a2  : 8192 * 4          =   32768 B @ 0
    //   b2  : 4096 * 4          =   16384 B @ 32768
    //   apk : 8192 * 128 * 2    = 2097152 B @ 49152   (packed fragment layout)
    //   wpk : 4096 * 128 * 2    = 1048576 B @ 2146304
    char* ws = (char*)d_ws;
    float* a2 = (float*)(ws);
    float* b2 = (float*)(ws + 32768);
    __hip_bfloat16* apk = (__hip_bfloat16*)(ws + 49152);
    __hip_bfloat16* wpk = (__hip_bfloat16*)(ws + 49152 + 2097152);

    som_prep<<<dim3((NB + NMN) / 16), dim3(256), 0, stream>>>(batch, weights, apk, wpk, a2, b2);

    som_gemm<<<dim3(2048), dim3(256), 0, stream>>>(apk, wpk, a2, b2, out);
}